// Round 12
// baseline (292.518 us; speedup 1.0000x reference)
//
#include <hip/hip_runtime.h>
#include <stdint.h>

// ---------- types ----------
typedef __attribute__((ext_vector_type(8))) __bf16 bf16x8;   // MFMA A/B frag (4 VGPRs)
typedef __attribute__((ext_vector_type(4))) float  floatx4;  // MFMA C/D frag
typedef __attribute__((ext_vector_type(4))) unsigned int uint4v;
typedef __attribute__((ext_vector_type(2))) unsigned int uint2v;
typedef __attribute__((ext_vector_type(4))) float  float4v;
typedef __attribute__((ext_vector_type(2))) _Float16 half2v;
typedef unsigned int u32;

__device__ __forceinline__ unsigned short f2bf(float f) {
  union { float f; unsigned int u; } x; x.f = f;
  unsigned int r = x.u + 0x7fffu + ((x.u >> 16) & 1u);  // RNE
  return (unsigned short)(r >> 16);
}

// async global->LDS, 16B per lane; dest = wave-uniform base + lane*16
__device__ __forceinline__ void gll16(const unsigned short* g, unsigned short* l) {
  __builtin_amdgcn_global_load_lds(
      (const __attribute__((address_space(1))) unsigned int*)g,
      (__attribute__((address_space(3))) unsigned int*)l, 16, 0, 0);
}

// ---------------- kernel 0: reshape w1 -> Wfmt[k-octet qg][n][8] bf16 --------
__global__ __launch_bounds__(256) void convert_kernel(
    const float* __restrict__ w1, unsigned short* __restrict__ Wfmt) {
  const int n  = blockIdx.x * 256 + threadIdx.x;  // 0..1535 (6 blocks in x)
  const int qg = blockIdx.y;                      // 0..191
  const float* src = w1 + (size_t)(qg * 8) * 1536 + n;
  uint4v o;
#pragma unroll
  for (int a = 0; a < 4; ++a) {
    u32 lo = f2bf(src[(size_t)(2 * a) * 1536]);
    u32 hi = f2bf(src[(size_t)(2 * a + 1) * 1536]);
    o[a] = lo | (hi << 16);
  }
  *(uint4v*)(Wfmt + ((size_t)qg * 1536 + n) * 8) = o;
}

// ---------------- kernel 2+1 fused: proj v4 + logits + out-init --------------
// ws epilogue stores F16 (match staging is a pure copy).
__global__ __launch_bounds__(256) void proj_kernel(
    const float* __restrict__ hidden, const unsigned short* __restrict__ Wfmt,
    const float* __restrict__ b1, unsigned short* __restrict__ wsR,
    unsigned short* __restrict__ wsC,
    const float* __restrict__ w_start, const float* __restrict__ b_start,
    const float* __restrict__ w_end, const float* __restrict__ b_end,
    const float* __restrict__ b2, float* __restrict__ out) {
  const int tid  = threadIdx.x;
  if (blockIdx.y == 16) {   // ---- fused logits + init (wave-uniform) ----
    if (blockIdx.x >= 32) {  // init 131072 floats with b2 over 16 blocks
      float v = b2[0];
      float4v vv = {v, v, v, v};
      int base = (blockIdx.x - 32) * 8192 + tid * 4;
#pragma unroll
      for (int itr = 0; itr < 8; ++itr)
        *(float4v*)(out + 1024 + base + itr * 1024) = vv;
      return;
    }
    const int lane = tid & 63;
    const int wv   = tid >> 6;
    const int wg   = blockIdx.x * 4 + wv;
    float wsv[12], wev[12];
#pragma unroll
    for (int t = 0; t < 12; ++t) {
      wsv[t] = w_start[lane + 64 * t];
      wev[t] = w_end[lane + 64 * t];
    }
    const float bs = b_start[0];
    const float be = b_end[0];
#pragma unroll
    for (int r = 0; r < 4; ++r) {
      int row = wg * 4 + r;
      const float* h = hidden + (size_t)row * 768;
      float ps = 0.f, pe = 0.f;
#pragma unroll
      for (int t = 0; t < 12; ++t) {
        float hv = h[lane + 64 * t];
        ps += hv * wsv[t];
        pe += hv * wev[t];
      }
#pragma unroll
      for (int off = 32; off >= 1; off >>= 1) {
        ps += __shfl_xor(ps, off, 64);
        pe += __shfl_xor(pe, off, 64);
      }
      if (lane == 0) { out[row] = ps + bs; out[512 + row] = pe + be; }
    }
    return;
  }

  // ---- proj proper: 32x64 tile, BK=64 (12 iters), dbuf LDS ----
  __shared__ unsigned short As2[2][8 * 32 * 8];
  __shared__ unsigned short Bs2[2][8 * 64 * 8];

  const int lane = tid & 63;
  const int wave = tid >> 6;
  const int wr = wave >> 1, wc = wave & 1;
  const int m0 = blockIdx.y * 32;
  const int n0g = blockIdx.x * 64;
  const bool isR = (n0g < 1536);
  const int qgb = isR ? 0 : 96;             // k-octet base in Wfmt
  const int n0 = isR ? n0g : (n0g - 1536);
  const int q4 = lane >> 4, l15 = lane & 15;

  floatx4 acc0 = {}, acc1 = {};

  const int a_row = tid >> 3;
  const int a_s   = tid & 7;
  const int aqh   = a_s >> 1;               // 0..3 within a 32-k half
  const int aj    = (a_s & 1) * 4;
  const float* hrow = hidden + (size_t)(m0 + a_row) * 768 + a_s * 4;

  const unsigned short* gB0 = Wfmt + ((size_t)(qgb + 2 * wave) * 1536 + n0 + lane) * 8;
  const unsigned short* gB1 = Wfmt + ((size_t)(qgb + 2 * wave + 1) * 1536 + n0 + lane) * 8;
  const size_t bstep = (size_t)8 * 1536 * 8;   // shorts per kb
  unsigned short* lB0 = &Bs2[0][(2 * wave) * 512];
  unsigned short* lB1 = &Bs2[0][(2 * wave + 1) * 512];
  unsigned short* lB0b = &Bs2[1][(2 * wave) * 512];
  unsigned short* lB1b = &Bs2[1][(2 * wave + 1) * 512];

#define PACKA(BUF, H, V)                                                     \
  {                                                                          \
    uint2v au_;                                                              \
    au_[0] = (u32)f2bf((V)[0]) | ((u32)f2bf((V)[1]) << 16);                  \
    au_[1] = (u32)f2bf((V)[2]) | ((u32)f2bf((V)[3]) << 16);                  \
    *(uint2v*)(&As2[BUF][(((H) * 4 + aqh) * 32 + a_row) * 8 + aj]) = au_;    \
  }

#define COMPUTE(BUF)                                                         \
  {                                                                          \
    _Pragma("unroll")                                                        \
    for (int ko2 = 0; ko2 < 2; ++ko2) {                                      \
      int qf = ko2 * 4 + q4;                                                 \
      bf16x8 af  = *(const bf16x8*)(&As2[BUF][(qf * 32 + 16 * wr + l15) * 8]); \
      bf16x8 bg0 = *(const bf16x8*)(&Bs2[BUF][(qf * 64 + 32 * wc + l15) * 8]); \
      bf16x8 bg1 = *(const bf16x8*)(&Bs2[BUF][(qf * 64 + 32 * wc + 16 + l15) * 8]); \
      acc0 = __builtin_amdgcn_mfma_f32_16x16x32_bf16(af, bg0, acc0, 0, 0, 0); \
      acc1 = __builtin_amdgcn_mfma_f32_16x16x32_bf16(af, bg1, acc1, 0, 0, 0); \
    }                                                                        \
  }

  // ---- prologue ----
  gll16(gB0, lB0);
  gll16(gB1, lB1);
  float4v sA0 = *(const float4v*)(hrow);
  float4v sA1 = *(const float4v*)(hrow + 32);
  PACKA(0, 0, sA0); PACKA(0, 1, sA1);
  float4v sB0 = *(const float4v*)(hrow + 64);
  float4v sB1 = *(const float4v*)(hrow + 96);
  __syncthreads();

#pragma unroll
  for (int kb = 0; kb < 12; kb += 2) {
    if (kb + 1 < 12) {
      gll16(gB0 + (size_t)(kb + 1) * bstep, lB0b);
      gll16(gB1 + (size_t)(kb + 1) * bstep, lB1b);
      PACKA(1, 0, sB0); PACKA(1, 1, sB1);
    }
    if (kb + 2 < 12) {
      sA0 = *(const float4v*)(hrow + (kb + 2) * 64);
      sA1 = *(const float4v*)(hrow + (kb + 2) * 64 + 32);
    }
    COMPUTE(0);
    __syncthreads();
    if (kb + 2 < 12) {
      gll16(gB0 + (size_t)(kb + 2) * bstep, lB0);
      gll16(gB1 + (size_t)(kb + 2) * bstep, lB1);
      PACKA(0, 0, sA0); PACKA(0, 1, sA1);
    }
    if (kb + 3 < 12) {
      sB0 = *(const float4v*)(hrow + (kb + 3) * 64);
      sB1 = *(const float4v*)(hrow + (kb + 3) * 64 + 32);
    }
    if (kb + 1 < 12) COMPUTE(1);
    __syncthreads();
  }
#undef PACKA
#undef COMPUTE

  unsigned short* outp = isR ? wsR : wsC;
#pragma unroll
  for (int ni = 0; ni < 2; ++ni) {
    const floatx4& ac = ni ? acc1 : acc0;
    int col = n0 + 32 * wc + 16 * ni + l15;
    float bias = isR ? b1[col] : 0.0f;
#pragma unroll
    for (int r = 0; r < 4; ++r) {
      int rowg = m0 + 16 * wr + q4 * 4 + r;
      _Float16 h = (_Float16)(ac[r] + bias);   // F16 RNE store
      outp[(size_t)rowg * 1536 + col] = __builtin_bit_cast(unsigned short, h);
    }
  }
}

// ---------------- kernel 3: match v11 — v7 skeleton, 1024 threads ------------
// R11 post-mortem: v10 spilled (FETCH 54MB, VALUBusy 0.4%). Best-ever = v7
// (R8, ~38us) at only 2 waves/SIMD. v11 = v7 geometry (256 blocks, 1/CU,
// band=384k, 3 chunks of 128k, dbuf, T14) but 1024 threads -> 4 waves/SIMD,
// half the per-thread state (2 accs, VGPR well under 128 -> no spill).
// All staging convergent (R rows written twice with identical bytes: benign).
__device__ __forceinline__ u32 ph_add(u32 a, u32 b) {
  u32 d; asm("v_pk_add_f16 %0, %1, %2" : "=v"(d) : "v"(a), "v"(b)); return d;
}
__device__ __forceinline__ u32 ph_mul(u32 a, u32 b) {
  u32 d; asm("v_pk_mul_f16 %0, %1, %2" : "=v"(d) : "v"(a), "v"(b)); return d;
}
__device__ __forceinline__ u32 ph_fma(u32 a, u32 b, u32 c) {
  u32 d; asm("v_pk_fma_f16 %0, %1, %2, %3" : "=v"(d) : "v"(a), "v"(b), "v"(c)); return d;
}
__device__ __forceinline__ u32 ph_max(u32 a, u32 b) {
  u32 d; asm("v_pk_max_f16 %0, %1, %2" : "=v"(d) : "v"(a), "v"(b)); return d;
}
__device__ __forceinline__ u32 ph_min(u32 a, u32 b) {
  u32 d; asm("v_pk_min_f16 %0, %1, %2" : "=v"(d) : "v"(a), "v"(b)); return d;
}
__device__ __forceinline__ u32 h2c(float f) {
  _Float16 h = (_Float16)f;
  unsigned short s = __builtin_bit_cast(unsigned short, h);
  return (u32)s | ((u32)s << 16);
}

__device__ __forceinline__ void gelu_pair(float& acc, u32 r, u32 c, u32 w,
                                          u32 C0c, u32 C1c, u32 C2c, u32 C3c,
                                          u32 LOc, u32 HIc, u32 Hc) {
  u32 x  = ph_add(r, c);
  u32 xc = ph_min(ph_max(x, LOc), HIc);
  u32 u  = ph_mul(xc, xc);
  u32 p  = ph_fma(u, ph_fma(u, ph_fma(u, C3c, C2c), C1c), C0c);
  u32 t  = ph_fma(xc, p, Hc);
  u32 g  = ph_mul(x, t);
  acc = __builtin_amdgcn_fdot2(__builtin_bit_cast(half2v, g),
                               __builtin_bit_cast(half2v, w), acc, false);
}

__global__ __launch_bounds__(1024) void match_kernel(
    const unsigned short* __restrict__ wsR,   // f16
    const unsigned short* __restrict__ wsC,   // f16
    const float* __restrict__ w2,
    float* __restrict__ outm) {
  // chunk = 128 k: row stride 68 u32 (128 f16 + 8 pad). 52.7 KB total.
  __shared__ u32 RsU[2][32 * 68];
  __shared__ u32 CsU[2][64 * 68];
  __shared__ u32 WsU[2][64];

  const int tid = threadIdx.x;
  const int jt = blockIdx.x;               // 0..3 -> 64 cols
  const int it = blockIdx.y;               // 0..7 -> 32 rows
  const int bz = blockIdx.z >> 2;          // batch
  const int kb4 = blockIdx.z & 3;          // 384-k band
  const int Kb0 = kb4 * 384;

  const int row  = tid >> 5;               // 0..31 output row
  const int cg   = tid & 31;               // cols {cg, cg+32}
  const int srow = tid >> 4;               // 0..63 staging row
  const int sseg = tid & 15;               // 8-f16 k-segment (16 per 128k)

  const u32 C0c = h2c(0.39103831f);
  const u32 C1c = h2c(-0.05415410f);
  const u32 C2c = h2c(0.00461682f);
  const u32 C3c = h2c(-1.51033e-4f);
  const u32 LOc = h2c(-3.5f);
  const u32 HIc = h2c(3.5f);
  const u32 Hc  = h2c(0.5f);

  float a0 = 0.f, a1 = 0.f;

  // R: rows 0..31 -> (srow&31) makes both halves load identical data; the
  // duplicate LDS write stores identical bytes (benign). C: 64 rows, unique.
  const unsigned short* gR =
      wsR + (size_t)(bz * 256 + it * 32 + (srow & 31)) * 1536 + Kb0 + sseg * 8;
  const unsigned short* gC =
      wsC + (size_t)(bz * 256 + jt * 64 + srow) * 1536 + Kb0 + sseg * 8;

  auto wrbuf = [&](int buf, uint4v pR, uint4v pC, float w0, float w1v) {
    *(uint4v*)(&RsU[buf][(srow & 31) * 68 + sseg * 4]) = pR;
    *(uint4v*)(&CsU[buf][srow * 68 + sseg * 4]) = pC;
    if (tid < 64) {
      auto h = __builtin_amdgcn_cvt_pkrtz(w0, w1v);
      WsU[buf][tid] = __builtin_bit_cast(u32, h);
    }
  };
  auto comp = [&](int buf) {
    const u32* rap = &RsU[buf][row * 68];
    const u32* c0p = &CsU[buf][cg * 68];
    const u32* c1p = c0p + 32 * 68;
    const u32* wp  = &WsU[buf][0];
#pragma unroll
    for (int ks = 0; ks < 16; ++ks) {
      uint4v ra = *(const uint4v*)(rap + ks * 4);
      uint4v wv = *(const uint4v*)(wp + ks * 4);
      uint4v cv = *(const uint4v*)(c0p + ks * 4);
#pragma unroll
      for (int p = 0; p < 4; ++p)
        gelu_pair(a0, ra[p], cv[p], wv[p], C0c, C1c, C2c, C3c, LOc, HIc, Hc);
      uint4v cw = *(const uint4v*)(c1p + ks * 4);
#pragma unroll
      for (int p = 0; p < 4; ++p)
        gelu_pair(a1, ra[p], cw[p], wv[p], C0c, C1c, C2c, C3c, LOc, HIc, Hc);
    }
  };

  // ---- chunk 0 load + write buf0 ----
  uint4v pR = *(const uint4v*)(gR);
  uint4v pC = *(const uint4v*)(gC);
  float pw0 = 0.f, pw1 = 0.f;
  if (tid < 64) { pw0 = w2[Kb0 + 2 * tid]; pw1 = w2[Kb0 + 2 * tid + 1]; }
  wrbuf(0, pR, pC, pw0, pw1);
  __syncthreads();

  // ---- issue chunk 1 loads (T14), compute chunk 0, write buf1 ----
  pR = *(const uint4v*)(gR + 128);
  pC = *(const uint4v*)(gC + 128);
  if (tid < 64) { pw0 = w2[Kb0 + 128 + 2 * tid]; pw1 = w2[Kb0 + 128 + 2 * tid + 1]; }
  comp(0);
  wrbuf(1, pR, pC, pw0, pw1);
  __syncthreads();

  // ---- issue chunk 2 loads, compute chunk 1, write buf0 ----
  pR = *(const uint4v*)(gR + 256);
  pC = *(const uint4v*)(gC + 256);
  if (tid < 64) { pw0 = w2[Kb0 + 256 + 2 * tid]; pw1 = w2[Kb0 + 256 + 2 * tid + 1]; }
  comp(1);
  wrbuf(0, pR, pC, pw0, pw1);
  __syncthreads();

  // ---- compute chunk 2 ----
  comp(0);

  // ---- epilogue: 2 partial sums -> atomics (4 contributions/addr) ----
  const size_t rowA = (size_t)(bz * 256 + it * 32 + row);
  const size_t base = rowA * 256 + jt * 64 + cg;
  unsafeAtomicAdd(&outm[base +  0], a0);
  unsafeAtomicAdd(&outm[base + 32], a1);
}

// ---------------- launch ----------------
extern "C" void kernel_launch(void* const* d_in, const int* in_sizes, int n_in,
                              void* d_out, int out_size, void* d_ws, size_t ws_size,
                              hipStream_t stream) {
  const float* hidden  = (const float*)d_in[0];
  const float* w_start = (const float*)d_in[1];
  const float* b_start = (const float*)d_in[2];
  const float* w_end   = (const float*)d_in[3];
  const float* b_end   = (const float*)d_in[4];
  const float* w1      = (const float*)d_in[5];
  const float* b1      = (const float*)d_in[6];
  const float* w2      = (const float*)d_in[7];
  const float* b2      = (const float*)d_in[8];

  float* out = (float*)d_out;
  char* ws = (char*)d_ws;
  unsigned short* wsR  = (unsigned short*)(ws);             // 1,572,864 B (f16)
  unsigned short* wsC  = (unsigned short*)(ws + 1572864);   // 1,572,864 B (f16)
  unsigned short* Wfmt = (unsigned short*)(ws + 3145728);   // 4,718,592 B (bf16)

  convert_kernel<<<dim3(6, 192), dim3(256), 0, stream>>>(w1, Wfmt);
  proj_kernel<<<dim3(48, 17), dim3(256), 0, stream>>>(
      hidden, Wfmt, b1, wsR, wsC, w_start, b_start, w_end, b_end, b2, out);
  match_kernel<<<dim3(4, 8, 8), dim3(1024), 0, stream>>>(wsR, wsC, w2, out + 1024);
}

// Round 13
// 124.842 us; speedup vs baseline: 2.3431x; 2.3431x over previous
//
#include <hip/hip_runtime.h>
#include <stdint.h>

// ---------- types ----------
typedef __attribute__((ext_vector_type(8))) __bf16 bf16x8;   // MFMA A/B frag (4 VGPRs)
typedef __attribute__((ext_vector_type(4))) float  floatx4;  // MFMA C/D frag
typedef __attribute__((ext_vector_type(4))) unsigned int uint4v;
typedef __attribute__((ext_vector_type(2))) unsigned int uint2v;
typedef __attribute__((ext_vector_type(4))) float  float4v;
typedef __attribute__((ext_vector_type(2))) _Float16 half2v;
typedef unsigned int u32;

__device__ __forceinline__ unsigned short f2bf(float f) {
  union { float f; unsigned int u; } x; x.f = f;
  unsigned int r = x.u + 0x7fffu + ((x.u >> 16) & 1u);  // RNE
  return (unsigned short)(r >> 16);
}

// async global->LDS, 16B per lane; dest = wave-uniform base + lane*16
__device__ __forceinline__ void gll16(const unsigned short* g, unsigned short* l) {
  __builtin_amdgcn_global_load_lds(
      (const __attribute__((address_space(1))) unsigned int*)g,
      (__attribute__((address_space(3))) unsigned int*)l, 16, 0, 0);
}

// ---------------- kernel 0: reshape w1 -> Wfmt[k-octet qg][n][8] bf16 --------
__global__ __launch_bounds__(256) void convert_kernel(
    const float* __restrict__ w1, unsigned short* __restrict__ Wfmt) {
  const int n  = blockIdx.x * 256 + threadIdx.x;  // 0..1535 (6 blocks in x)
  const int qg = blockIdx.y;                      // 0..191
  const float* src = w1 + (size_t)(qg * 8) * 1536 + n;
  uint4v o;
#pragma unroll
  for (int a = 0; a < 4; ++a) {
    u32 lo = f2bf(src[(size_t)(2 * a) * 1536]);
    u32 hi = f2bf(src[(size_t)(2 * a + 1) * 1536]);
    o[a] = lo | (hi << 16);
  }
  *(uint4v*)(Wfmt + ((size_t)qg * 1536 + n) * 8) = o;
}

// ---------------- kernel 2+1 fused: proj v4 + logits + out-init --------------
// ws epilogue stores F16 (match staging is a pure copy).
__global__ __launch_bounds__(256) void proj_kernel(
    const float* __restrict__ hidden, const unsigned short* __restrict__ Wfmt,
    const float* __restrict__ b1, unsigned short* __restrict__ wsR,
    unsigned short* __restrict__ wsC,
    const float* __restrict__ w_start, const float* __restrict__ b_start,
    const float* __restrict__ w_end, const float* __restrict__ b_end,
    const float* __restrict__ b2, float* __restrict__ out) {
  const int tid  = threadIdx.x;
  if (blockIdx.y == 16) {   // ---- fused logits + init (wave-uniform) ----
    if (blockIdx.x >= 32) {  // init 131072 floats with b2 over 16 blocks
      float v = b2[0];
      float4v vv = {v, v, v, v};
      int base = (blockIdx.x - 32) * 8192 + tid * 4;
#pragma unroll
      for (int itr = 0; itr < 8; ++itr)
        *(float4v*)(out + 1024 + base + itr * 1024) = vv;
      return;
    }
    const int lane = tid & 63;
    const int wv   = tid >> 6;
    const int wg   = blockIdx.x * 4 + wv;
    float wsv[12], wev[12];
#pragma unroll
    for (int t = 0; t < 12; ++t) {
      wsv[t] = w_start[lane + 64 * t];
      wev[t] = w_end[lane + 64 * t];
    }
    const float bs = b_start[0];
    const float be = b_end[0];
#pragma unroll
    for (int r = 0; r < 4; ++r) {
      int row = wg * 4 + r;
      const float* h = hidden + (size_t)row * 768;
      float ps = 0.f, pe = 0.f;
#pragma unroll
      for (int t = 0; t < 12; ++t) {
        float hv = h[lane + 64 * t];
        ps += hv * wsv[t];
        pe += hv * wev[t];
      }
#pragma unroll
      for (int off = 32; off >= 1; off >>= 1) {
        ps += __shfl_xor(ps, off, 64);
        pe += __shfl_xor(pe, off, 64);
      }
      if (lane == 0) { out[row] = ps + bs; out[512 + row] = pe + be; }
    }
    return;
  }

  // ---- proj proper: 32x64 tile, BK=64 (12 iters), dbuf LDS ----
  __shared__ unsigned short As2[2][8 * 32 * 8];
  __shared__ unsigned short Bs2[2][8 * 64 * 8];

  const int lane = tid & 63;
  const int wave = tid >> 6;
  const int wr = wave >> 1, wc = wave & 1;
  const int m0 = blockIdx.y * 32;
  const int n0g = blockIdx.x * 64;
  const bool isR = (n0g < 1536);
  const int qgb = isR ? 0 : 96;             // k-octet base in Wfmt
  const int n0 = isR ? n0g : (n0g - 1536);
  const int q4 = lane >> 4, l15 = lane & 15;

  floatx4 acc0 = {}, acc1 = {};

  const int a_row = tid >> 3;
  const int a_s   = tid & 7;
  const int aqh   = a_s >> 1;               // 0..3 within a 32-k half
  const int aj    = (a_s & 1) * 4;
  const float* hrow = hidden + (size_t)(m0 + a_row) * 768 + a_s * 4;

  const unsigned short* gB0 = Wfmt + ((size_t)(qgb + 2 * wave) * 1536 + n0 + lane) * 8;
  const unsigned short* gB1 = Wfmt + ((size_t)(qgb + 2 * wave + 1) * 1536 + n0 + lane) * 8;
  const size_t bstep = (size_t)8 * 1536 * 8;   // shorts per kb
  unsigned short* lB0 = &Bs2[0][(2 * wave) * 512];
  unsigned short* lB1 = &Bs2[0][(2 * wave + 1) * 512];
  unsigned short* lB0b = &Bs2[1][(2 * wave) * 512];
  unsigned short* lB1b = &Bs2[1][(2 * wave + 1) * 512];

#define PACKA(BUF, H, V)                                                     \
  {                                                                          \
    uint2v au_;                                                              \
    au_[0] = (u32)f2bf((V)[0]) | ((u32)f2bf((V)[1]) << 16);                  \
    au_[1] = (u32)f2bf((V)[2]) | ((u32)f2bf((V)[3]) << 16);                  \
    *(uint2v*)(&As2[BUF][(((H) * 4 + aqh) * 32 + a_row) * 8 + aj]) = au_;    \
  }

#define COMPUTE(BUF)                                                         \
  {                                                                          \
    _Pragma("unroll")                                                        \
    for (int ko2 = 0; ko2 < 2; ++ko2) {                                      \
      int qf = ko2 * 4 + q4;                                                 \
      bf16x8 af  = *(const bf16x8*)(&As2[BUF][(qf * 32 + 16 * wr + l15) * 8]); \
      bf16x8 bg0 = *(const bf16x8*)(&Bs2[BUF][(qf * 64 + 32 * wc + l15) * 8]); \
      bf16x8 bg1 = *(const bf16x8*)(&Bs2[BUF][(qf * 64 + 32 * wc + 16 + l15) * 8]); \
      acc0 = __builtin_amdgcn_mfma_f32_16x16x32_bf16(af, bg0, acc0, 0, 0, 0); \
      acc1 = __builtin_amdgcn_mfma_f32_16x16x32_bf16(af, bg1, acc1, 0, 0, 0); \
    }                                                                        \
  }

  // ---- prologue ----
  gll16(gB0, lB0);
  gll16(gB1, lB1);
  float4v sA0 = *(const float4v*)(hrow);
  float4v sA1 = *(const float4v*)(hrow + 32);
  PACKA(0, 0, sA0); PACKA(0, 1, sA1);
  float4v sB0 = *(const float4v*)(hrow + 64);
  float4v sB1 = *(const float4v*)(hrow + 96);
  __syncthreads();

#pragma unroll
  for (int kb = 0; kb < 12; kb += 2) {
    if (kb + 1 < 12) {
      gll16(gB0 + (size_t)(kb + 1) * bstep, lB0b);
      gll16(gB1 + (size_t)(kb + 1) * bstep, lB1b);
      PACKA(1, 0, sB0); PACKA(1, 1, sB1);
    }
    if (kb + 2 < 12) {
      sA0 = *(const float4v*)(hrow + (kb + 2) * 64);
      sA1 = *(const float4v*)(hrow + (kb + 2) * 64 + 32);
    }
    COMPUTE(0);
    __syncthreads();
    if (kb + 2 < 12) {
      gll16(gB0 + (size_t)(kb + 2) * bstep, lB0);
      gll16(gB1 + (size_t)(kb + 2) * bstep, lB1);
      PACKA(0, 0, sA0); PACKA(0, 1, sA1);
    }
    if (kb + 3 < 12) {
      sB0 = *(const float4v*)(hrow + (kb + 3) * 64);
      sB1 = *(const float4v*)(hrow + (kb + 3) * 64 + 32);
    }
    if (kb + 1 < 12) COMPUTE(1);
    __syncthreads();
  }
#undef PACKA
#undef COMPUTE

  unsigned short* outp = isR ? wsR : wsC;
#pragma unroll
  for (int ni = 0; ni < 2; ++ni) {
    const floatx4& ac = ni ? acc1 : acc0;
    int col = n0 + 32 * wc + 16 * ni + l15;
    float bias = isR ? b1[col] : 0.0f;
#pragma unroll
    for (int r = 0; r < 4; ++r) {
      int rowg = m0 + 16 * wr + q4 * 4 + r;
      _Float16 h = (_Float16)(ac[r] + bias);   // F16 RNE store
      outp[(size_t)rowg * 1536 + col] = __builtin_bit_cast(unsigned short, h);
    }
  }
}

// ---------------- kernel 3: match v12 — v7 pipeline + f16 pure-copy staging --
// Merge of two PROVEN pieces: v7 geometry/pipeline (R8, best total 123.59,
// 512thr, 256 blocks = 1/CU single round, band=384k, 3 chunks of 128k, dbuf,
// T14, no spill) + f16-ws copy staging (R9, VGPR=100 no spill) which deletes
// the 36 pk-ALU bf16->f16 convert from the inter-barrier critical path.
__device__ __forceinline__ u32 ph_add(u32 a, u32 b) {
  u32 d; asm("v_pk_add_f16 %0, %1, %2" : "=v"(d) : "v"(a), "v"(b)); return d;
}
__device__ __forceinline__ u32 ph_mul(u32 a, u32 b) {
  u32 d; asm("v_pk_mul_f16 %0, %1, %2" : "=v"(d) : "v"(a), "v"(b)); return d;
}
__device__ __forceinline__ u32 ph_fma(u32 a, u32 b, u32 c) {
  u32 d; asm("v_pk_fma_f16 %0, %1, %2, %3" : "=v"(d) : "v"(a), "v"(b), "v"(c)); return d;
}
__device__ __forceinline__ u32 ph_max(u32 a, u32 b) {
  u32 d; asm("v_pk_max_f16 %0, %1, %2" : "=v"(d) : "v"(a), "v"(b)); return d;
}
__device__ __forceinline__ u32 ph_min(u32 a, u32 b) {
  u32 d; asm("v_pk_min_f16 %0, %1, %2" : "=v"(d) : "v"(a), "v"(b)); return d;
}
__device__ __forceinline__ u32 h2c(float f) {
  _Float16 h = (_Float16)f;
  unsigned short s = __builtin_bit_cast(unsigned short, h);
  return (u32)s | ((u32)s << 16);
}

__device__ __forceinline__ void gelu_pair(float& acc, u32 r, u32 c, u32 w,
                                          u32 C0c, u32 C1c, u32 C2c, u32 C3c,
                                          u32 LOc, u32 HIc, u32 Hc) {
  u32 x  = ph_add(r, c);
  u32 xc = ph_min(ph_max(x, LOc), HIc);
  u32 u  = ph_mul(xc, xc);
  u32 p  = ph_fma(u, ph_fma(u, ph_fma(u, C3c, C2c), C1c), C0c);
  u32 t  = ph_fma(xc, p, Hc);
  u32 g  = ph_mul(x, t);
  acc = __builtin_amdgcn_fdot2(__builtin_bit_cast(half2v, g),
                               __builtin_bit_cast(half2v, w), acc, false);
}

__global__ __launch_bounds__(512) void match_kernel(
    const unsigned short* __restrict__ wsR,   // f16
    const unsigned short* __restrict__ wsC,   // f16
    const float* __restrict__ w2,
    float* __restrict__ outm) {
  // f16 tiles, chunk=128k: row stride 68 u32 (64 data + 4 pad). dbuf 52.7 KB.
  __shared__ u32 RsU[2][32 * 68];
  __shared__ u32 CsU[2][64 * 68];
  __shared__ u32 WsU[2][64];

  const int tid = threadIdx.x;
  const int jt = blockIdx.x;              // 0..3 -> 64 cols
  const int it = blockIdx.y;              // 0..7 -> 32 rows
  const int bz = blockIdx.z >> 2;         // batch
  const int kb4 = blockIdx.z & 3;         // 384-k band
  const int Kb0 = kb4 * 384;

  const int rg  = tid >> 5;               // 0..15: rows {2rg, 2rg+1}
  const int cg  = tid & 31;               // cols {cg, cg+32}
  const int srow = tid >> 4;              // 0..31 staging row
  const int sseg = tid & 15;              // 8-f16 k-segment (16 per 128k)

  const u32 C0c = h2c(0.39103831f);
  const u32 C1c = h2c(-0.05415410f);
  const u32 C2c = h2c(0.00461682f);
  const u32 C3c = h2c(-1.51033e-4f);
  const u32 LOc = h2c(-3.5f);
  const u32 HIc = h2c(3.5f);
  const u32 Hc  = h2c(0.5f);

  float a0 = 0.f, a1 = 0.f, b0 = 0.f, b1 = 0.f;

  const unsigned short* gR  = wsR + (size_t)(bz * 256 + it * 32 + srow) * 1536 + Kb0 + sseg * 8;
  const unsigned short* gC0 = wsC + (size_t)(bz * 256 + jt * 64 + srow) * 1536 + Kb0 + sseg * 8;
  const unsigned short* gC1 = gC0 + (size_t)32 * 1536;

  // stage-write: PURE COPY (f16 ws), no conversion ALU
  auto wr = [&](int buf, uint4v pR, uint4v pC0, uint4v pC1, float w0, float w1) {
    *(uint4v*)(&RsU[buf][srow * 68 + sseg * 4]) = pR;
    *(uint4v*)(&CsU[buf][srow * 68 + sseg * 4]) = pC0;
    *(uint4v*)(&CsU[buf][(srow + 32) * 68 + sseg * 4]) = pC1;
    if (tid < 64) {
      auto h = __builtin_amdgcn_cvt_pkrtz(w0, w1);
      WsU[buf][tid] = __builtin_bit_cast(u32, h);
    }
  };
  auto comp = [&](int buf) {
    const u32* rap = &RsU[buf][(2 * rg) * 68];
    const u32* rbp = rap + 68;
    const u32* c0p = &CsU[buf][cg * 68];
    const u32* c1p = c0p + 32 * 68;
    const u32* wp  = &WsU[buf][0];
#pragma unroll 4
    for (int ks = 0; ks < 16; ++ks) {
      uint4v ra = *(const uint4v*)(rap + ks * 4);
      uint4v rb = *(const uint4v*)(rbp + ks * 4);
      uint4v wv = *(const uint4v*)(wp + ks * 4);
      uint4v cv = *(const uint4v*)(c0p + ks * 4);
#pragma unroll
      for (int p = 0; p < 4; ++p) {
        gelu_pair(a0, ra[p], cv[p], wv[p], C0c, C1c, C2c, C3c, LOc, HIc, Hc);
        gelu_pair(b0, rb[p], cv[p], wv[p], C0c, C1c, C2c, C3c, LOc, HIc, Hc);
      }
      uint4v cw = *(const uint4v*)(c1p + ks * 4);
#pragma unroll
      for (int p = 0; p < 4; ++p) {
        gelu_pair(a1, ra[p], cw[p], wv[p], C0c, C1c, C2c, C3c, LOc, HIc, Hc);
        gelu_pair(b1, rb[p], cw[p], wv[p], C0c, C1c, C2c, C3c, LOc, HIc, Hc);
      }
    }
  };

  // ---- chunk 0: load + write buf0 ----
  uint4v pR  = *(const uint4v*)(gR);
  uint4v pC0 = *(const uint4v*)(gC0);
  uint4v pC1 = *(const uint4v*)(gC1);
  float pw0 = 0.f, pw1 = 0.f;
  if (tid < 64) { pw0 = w2[Kb0 + 2 * tid]; pw1 = w2[Kb0 + 2 * tid + 1]; }
  wr(0, pR, pC0, pC1, pw0, pw1);
  __syncthreads();

  // ---- prefetch chunk 1, compute chunk 0 ----
  pR  = *(const uint4v*)(gR + 128);
  pC0 = *(const uint4v*)(gC0 + 128);
  pC1 = *(const uint4v*)(gC1 + 128);
  if (tid < 64) { pw0 = w2[Kb0 + 128 + 2 * tid]; pw1 = w2[Kb0 + 128 + 2 * tid + 1]; }
  comp(0);
  wr(1, pR, pC0, pC1, pw0, pw1);
  __syncthreads();

  // ---- prefetch chunk 2, compute chunk 1 ----
  pR  = *(const uint4v*)(gR + 256);
  pC0 = *(const uint4v*)(gC0 + 256);
  pC1 = *(const uint4v*)(gC1 + 256);
  if (tid < 64) { pw0 = w2[Kb0 + 256 + 2 * tid]; pw1 = w2[Kb0 + 256 + 2 * tid + 1]; }
  comp(1);
  wr(0, pR, pC0, pC1, pw0, pw1);
  __syncthreads();

  // ---- compute chunk 2 ----
  comp(0);

  // ---- epilogue: 4 partial sums -> atomics (4 contributions/addr) ----
  const size_t rowA = (size_t)(bz * 256 + it * 32 + 2 * rg);
  const size_t base = rowA * 256 + jt * 64 + cg;
  unsafeAtomicAdd(&outm[base +  0], a0);
  unsafeAtomicAdd(&outm[base + 32], a1);
  unsafeAtomicAdd(&outm[base + 256 +  0], b0);
  unsafeAtomicAdd(&outm[base + 256 + 32], b1);
}

// ---------------- launch ----------------
extern "C" void kernel_launch(void* const* d_in, const int* in_sizes, int n_in,
                              void* d_out, int out_size, void* d_ws, size_t ws_size,
                              hipStream_t stream) {
  const float* hidden  = (const float*)d_in[0];
  const float* w_start = (const float*)d_in[1];
  const float* b_start = (const float*)d_in[2];
  const float* w_end   = (const float*)d_in[3];
  const float* b_end   = (const float*)d_in[4];
  const float* w1      = (const float*)d_in[5];
  const float* b1      = (const float*)d_in[6];
  const float* w2      = (const float*)d_in[7];
  const float* b2      = (const float*)d_in[8];

  float* out = (float*)d_out;
  char* ws = (char*)d_ws;
  unsigned short* wsR  = (unsigned short*)(ws);             // 1,572,864 B (f16)
  unsigned short* wsC  = (unsigned short*)(ws + 1572864);   // 1,572,864 B (f16)
  unsigned short* Wfmt = (unsigned short*)(ws + 3145728);   // 4,718,592 B (bf16)

  convert_kernel<<<dim3(6, 192), dim3(256), 0, stream>>>(w1, Wfmt);
  proj_kernel<<<dim3(48, 17), dim3(256), 0, stream>>>(
      hidden, Wfmt, b1, wsR, wsC, w_start, b_start, w_end, b_end, b2, out);
  match_kernel<<<dim3(4, 8, 8), dim3(512), 0, stream>>>(wsR, wsC, w2, out + 1024);
}

// Round 14
// 123.368 us; speedup vs baseline: 2.3711x; 1.0119x over previous
//
#include <hip/hip_runtime.h>
#include <stdint.h>

// ---------- types ----------
typedef __attribute__((ext_vector_type(8))) __bf16 bf16x8;   // MFMA A/B frag (4 VGPRs)
typedef __attribute__((ext_vector_type(4))) float  floatx4;  // MFMA C/D frag
typedef __attribute__((ext_vector_type(4))) unsigned int uint4v;
typedef __attribute__((ext_vector_type(2))) unsigned int uint2v;
typedef __attribute__((ext_vector_type(4))) float  float4v;
typedef __attribute__((ext_vector_type(2))) _Float16 half2v;
typedef unsigned int u32;

__device__ __forceinline__ unsigned short f2bf(float f) {
  union { float f; unsigned int u; } x; x.f = f;
  unsigned int r = x.u + 0x7fffu + ((x.u >> 16) & 1u);  // RNE
  return (unsigned short)(r >> 16);
}

// async global->LDS, 16B per lane; dest = wave-uniform base + lane*16
__device__ __forceinline__ void gll16(const unsigned short* g, unsigned short* l) {
  __builtin_amdgcn_global_load_lds(
      (const __attribute__((address_space(1))) unsigned int*)g,
      (__attribute__((address_space(3))) unsigned int*)l, 16, 0, 0);
}

// ---------------- kernel 0: reshape w1 -> Wfmt[k-octet qg][n][8] bf16 --------
__global__ __launch_bounds__(256) void convert_kernel(
    const float* __restrict__ w1, unsigned short* __restrict__ Wfmt) {
  const int n  = blockIdx.x * 256 + threadIdx.x;  // 0..1535 (6 blocks in x)
  const int qg = blockIdx.y;                      // 0..191
  const float* src = w1 + (size_t)(qg * 8) * 1536 + n;
  uint4v o;
#pragma unroll
  for (int a = 0; a < 4; ++a) {
    u32 lo = f2bf(src[(size_t)(2 * a) * 1536]);
    u32 hi = f2bf(src[(size_t)(2 * a + 1) * 1536]);
    o[a] = lo | (hi << 16);
  }
  *(uint4v*)(Wfmt + ((size_t)qg * 1536 + n) * 8) = o;
}

// ---------------- kernel 2+1 fused: proj v4 + logits + out-init --------------
// ws epilogue stores F16 (match staging is a pure copy).
__global__ __launch_bounds__(256) void proj_kernel(
    const float* __restrict__ hidden, const unsigned short* __restrict__ Wfmt,
    const float* __restrict__ b1, unsigned short* __restrict__ wsR,
    unsigned short* __restrict__ wsC,
    const float* __restrict__ w_start, const float* __restrict__ b_start,
    const float* __restrict__ w_end, const float* __restrict__ b_end,
    const float* __restrict__ b2, float* __restrict__ out) {
  const int tid  = threadIdx.x;
  if (blockIdx.y == 16) {   // ---- fused logits + init (wave-uniform) ----
    if (blockIdx.x >= 32) {  // init 131072 floats with b2 over 16 blocks
      float v = b2[0];
      float4v vv = {v, v, v, v};
      int base = (blockIdx.x - 32) * 8192 + tid * 4;
#pragma unroll
      for (int itr = 0; itr < 8; ++itr)
        *(float4v*)(out + 1024 + base + itr * 1024) = vv;
      return;
    }
    const int lane = tid & 63;
    const int wv   = tid >> 6;
    const int wg   = blockIdx.x * 4 + wv;
    float wsv[12], wev[12];
#pragma unroll
    for (int t = 0; t < 12; ++t) {
      wsv[t] = w_start[lane + 64 * t];
      wev[t] = w_end[lane + 64 * t];
    }
    const float bs = b_start[0];
    const float be = b_end[0];
#pragma unroll
    for (int r = 0; r < 4; ++r) {
      int row = wg * 4 + r;
      const float* h = hidden + (size_t)row * 768;
      float ps = 0.f, pe = 0.f;
#pragma unroll
      for (int t = 0; t < 12; ++t) {
        float hv = h[lane + 64 * t];
        ps += hv * wsv[t];
        pe += hv * wev[t];
      }
#pragma unroll
      for (int off = 32; off >= 1; off >>= 1) {
        ps += __shfl_xor(ps, off, 64);
        pe += __shfl_xor(pe, off, 64);
      }
      if (lane == 0) { out[row] = ps + bs; out[512 + row] = pe + be; }
    }
    return;
  }

  // ---- proj proper: 32x64 tile, BK=64 (12 iters), dbuf LDS ----
  __shared__ unsigned short As2[2][8 * 32 * 8];
  __shared__ unsigned short Bs2[2][8 * 64 * 8];

  const int lane = tid & 63;
  const int wave = tid >> 6;
  const int wr = wave >> 1, wc = wave & 1;
  const int m0 = blockIdx.y * 32;
  const int n0g = blockIdx.x * 64;
  const bool isR = (n0g < 1536);
  const int qgb = isR ? 0 : 96;             // k-octet base in Wfmt
  const int n0 = isR ? n0g : (n0g - 1536);
  const int q4 = lane >> 4, l15 = lane & 15;

  floatx4 acc0 = {}, acc1 = {};

  const int a_row = tid >> 3;
  const int a_s   = tid & 7;
  const int aqh   = a_s >> 1;               // 0..3 within a 32-k half
  const int aj    = (a_s & 1) * 4;
  const float* hrow = hidden + (size_t)(m0 + a_row) * 768 + a_s * 4;

  const unsigned short* gB0 = Wfmt + ((size_t)(qgb + 2 * wave) * 1536 + n0 + lane) * 8;
  const unsigned short* gB1 = Wfmt + ((size_t)(qgb + 2 * wave + 1) * 1536 + n0 + lane) * 8;
  const size_t bstep = (size_t)8 * 1536 * 8;   // shorts per kb
  unsigned short* lB0 = &Bs2[0][(2 * wave) * 512];
  unsigned short* lB1 = &Bs2[0][(2 * wave + 1) * 512];
  unsigned short* lB0b = &Bs2[1][(2 * wave) * 512];
  unsigned short* lB1b = &Bs2[1][(2 * wave + 1) * 512];

#define PACKA(BUF, H, V)                                                     \
  {                                                                          \
    uint2v au_;                                                              \
    au_[0] = (u32)f2bf((V)[0]) | ((u32)f2bf((V)[1]) << 16);                  \
    au_[1] = (u32)f2bf((V)[2]) | ((u32)f2bf((V)[3]) << 16);                  \
    *(uint2v*)(&As2[BUF][(((H) * 4 + aqh) * 32 + a_row) * 8 + aj]) = au_;    \
  }

#define COMPUTE(BUF)                                                         \
  {                                                                          \
    _Pragma("unroll")                                                        \
    for (int ko2 = 0; ko2 < 2; ++ko2) {                                      \
      int qf = ko2 * 4 + q4;                                                 \
      bf16x8 af  = *(const bf16x8*)(&As2[BUF][(qf * 32 + 16 * wr + l15) * 8]); \
      bf16x8 bg0 = *(const bf16x8*)(&Bs2[BUF][(qf * 64 + 32 * wc + l15) * 8]); \
      bf16x8 bg1 = *(const bf16x8*)(&Bs2[BUF][(qf * 64 + 32 * wc + 16 + l15) * 8]); \
      acc0 = __builtin_amdgcn_mfma_f32_16x16x32_bf16(af, bg0, acc0, 0, 0, 0); \
      acc1 = __builtin_amdgcn_mfma_f32_16x16x32_bf16(af, bg1, acc1, 0, 0, 0); \
    }                                                                        \
  }

  // ---- prologue ----
  gll16(gB0, lB0);
  gll16(gB1, lB1);
  float4v sA0 = *(const float4v*)(hrow);
  float4v sA1 = *(const float4v*)(hrow + 32);
  PACKA(0, 0, sA0); PACKA(0, 1, sA1);
  float4v sB0 = *(const float4v*)(hrow + 64);
  float4v sB1 = *(const float4v*)(hrow + 96);
  __syncthreads();

#pragma unroll
  for (int kb = 0; kb < 12; kb += 2) {
    if (kb + 1 < 12) {
      gll16(gB0 + (size_t)(kb + 1) * bstep, lB0b);
      gll16(gB1 + (size_t)(kb + 1) * bstep, lB1b);
      PACKA(1, 0, sB0); PACKA(1, 1, sB1);
    }
    if (kb + 2 < 12) {
      sA0 = *(const float4v*)(hrow + (kb + 2) * 64);
      sA1 = *(const float4v*)(hrow + (kb + 2) * 64 + 32);
    }
    COMPUTE(0);
    __syncthreads();
    if (kb + 2 < 12) {
      gll16(gB0 + (size_t)(kb + 2) * bstep, lB0);
      gll16(gB1 + (size_t)(kb + 2) * bstep, lB1);
      PACKA(0, 0, sA0); PACKA(0, 1, sA1);
    }
    if (kb + 3 < 12) {
      sB0 = *(const float4v*)(hrow + (kb + 3) * 64);
      sB1 = *(const float4v*)(hrow + (kb + 3) * 64 + 32);
    }
    if (kb + 1 < 12) COMPUTE(1);
    __syncthreads();
  }
#undef PACKA
#undef COMPUTE

  unsigned short* outp = isR ? wsR : wsC;
#pragma unroll
  for (int ni = 0; ni < 2; ++ni) {
    const floatx4& ac = ni ? acc1 : acc0;
    int col = n0 + 32 * wc + 16 * ni + l15;
    float bias = isR ? b1[col] : 0.0f;
#pragma unroll
    for (int r = 0; r < 4; ++r) {
      int rowg = m0 + 16 * wr + q4 * 4 + r;
      _Float16 h = (_Float16)(ac[r] + bias);   // F16 RNE store
      outp[(size_t)rowg * 1536 + col] = __builtin_bit_cast(unsigned short, h);
    }
  }
}

// ---------------- kernel 3: match v13 — 16x64 tile, 2 blocks/CU single round -
// The untested occupancy cell: v7/v12 pipeline (proven clean) but tile halved
// to 16x64 -> 512 blocks = EXACTLY 2/CU, one residency round, 4 waves/SIMD.
// Per-thread state halved (2 accs; R-stage only for tid<256) -> VGPR well
// below the proven-clean 100. LDS 44 KB -> 2 blocks fit (88 < 160 KB).
__device__ __forceinline__ u32 ph_add(u32 a, u32 b) {
  u32 d; asm("v_pk_add_f16 %0, %1, %2" : "=v"(d) : "v"(a), "v"(b)); return d;
}
__device__ __forceinline__ u32 ph_mul(u32 a, u32 b) {
  u32 d; asm("v_pk_mul_f16 %0, %1, %2" : "=v"(d) : "v"(a), "v"(b)); return d;
}
__device__ __forceinline__ u32 ph_fma(u32 a, u32 b, u32 c) {
  u32 d; asm("v_pk_fma_f16 %0, %1, %2, %3" : "=v"(d) : "v"(a), "v"(b), "v"(c)); return d;
}
__device__ __forceinline__ u32 ph_max(u32 a, u32 b) {
  u32 d; asm("v_pk_max_f16 %0, %1, %2" : "=v"(d) : "v"(a), "v"(b)); return d;
}
__device__ __forceinline__ u32 ph_min(u32 a, u32 b) {
  u32 d; asm("v_pk_min_f16 %0, %1, %2" : "=v"(d) : "v"(a), "v"(b)); return d;
}
__device__ __forceinline__ u32 h2c(float f) {
  _Float16 h = (_Float16)f;
  unsigned short s = __builtin_bit_cast(unsigned short, h);
  return (u32)s | ((u32)s << 16);
}

__device__ __forceinline__ void gelu_pair(float& acc, u32 r, u32 c, u32 w,
                                          u32 C0c, u32 C1c, u32 C2c, u32 C3c,
                                          u32 LOc, u32 HIc, u32 Hc) {
  u32 x  = ph_add(r, c);
  u32 xc = ph_min(ph_max(x, LOc), HIc);
  u32 u  = ph_mul(xc, xc);
  u32 p  = ph_fma(u, ph_fma(u, ph_fma(u, C3c, C2c), C1c), C0c);
  u32 t  = ph_fma(xc, p, Hc);
  u32 g  = ph_mul(x, t);
  acc = __builtin_amdgcn_fdot2(__builtin_bit_cast(half2v, g),
                               __builtin_bit_cast(half2v, w), acc, false);
}

__global__ __launch_bounds__(512) void match_kernel(
    const unsigned short* __restrict__ wsR,   // f16
    const unsigned short* __restrict__ wsC,   // f16
    const float* __restrict__ w2,
    float* __restrict__ outm) {
  // f16 tiles, chunk=128k: row stride 68 u32 (64 data + 4 pad). 44 KB total.
  __shared__ u32 RsU[2][16 * 68];   // 2 x 4352 B
  __shared__ u32 CsU[2][64 * 68];   // 2 x 17408 B
  __shared__ u32 WsU[2][64];        // 2 x 256 B

  const int tid = threadIdx.x;
  const int jt = blockIdx.x;              // 0..3  -> 64 cols
  const int it = blockIdx.y;              // 0..15 -> 16 rows
  const int bz = blockIdx.z >> 2;         // batch
  const int kb4 = blockIdx.z & 3;         // 384-k band
  const int Kb0 = kb4 * 384;

  const int row = tid >> 5;               // 0..15 output row
  const int cg  = tid & 31;               // cols {cg, cg+32}
  const int srow = tid >> 4;              // 0..31 staging row (C); R uses &15
  const int sseg = tid & 15;              // 8-f16 k-segment (16 per 128k)
  const bool doR = (tid < 256);           // waves 0-3 stage R (wave-uniform)

  const u32 C0c = h2c(0.39103831f);
  const u32 C1c = h2c(-0.05415410f);
  const u32 C2c = h2c(0.00461682f);
  const u32 C3c = h2c(-1.51033e-4f);
  const u32 LOc = h2c(-3.5f);
  const u32 HIc = h2c(3.5f);
  const u32 Hc  = h2c(0.5f);

  float a0 = 0.f, a1 = 0.f;

  const unsigned short* gR  = wsR + (size_t)(bz * 256 + it * 16 + (srow & 15)) * 1536 + Kb0 + sseg * 8;
  const unsigned short* gC0 = wsC + (size_t)(bz * 256 + jt * 64 + srow) * 1536 + Kb0 + sseg * 8;
  const unsigned short* gC1 = gC0 + (size_t)32 * 1536;

  // stage-write: pure copy (f16 ws)
  auto wr = [&](int buf, uint4v pR, uint4v pC0, uint4v pC1, float w0, float w1) {
    if (doR) *(uint4v*)(&RsU[buf][(srow & 15) * 68 + sseg * 4]) = pR;
    *(uint4v*)(&CsU[buf][srow * 68 + sseg * 4]) = pC0;
    *(uint4v*)(&CsU[buf][(srow + 32) * 68 + sseg * 4]) = pC1;
    if (tid < 64) {
      auto h = __builtin_amdgcn_cvt_pkrtz(w0, w1);
      WsU[buf][tid] = __builtin_bit_cast(u32, h);
    }
  };
  auto comp = [&](int buf) {
    const u32* rap = &RsU[buf][row * 68];
    const u32* c0p = &CsU[buf][cg * 68];
    const u32* c1p = c0p + 32 * 68;
    const u32* wp  = &WsU[buf][0];
#pragma unroll 4
    for (int ks = 0; ks < 16; ++ks) {
      uint4v ra = *(const uint4v*)(rap + ks * 4);
      uint4v wv = *(const uint4v*)(wp + ks * 4);
      uint4v cv = *(const uint4v*)(c0p + ks * 4);
#pragma unroll
      for (int p = 0; p < 4; ++p)
        gelu_pair(a0, ra[p], cv[p], wv[p], C0c, C1c, C2c, C3c, LOc, HIc, Hc);
      uint4v cw = *(const uint4v*)(c1p + ks * 4);
#pragma unroll
      for (int p = 0; p < 4; ++p)
        gelu_pair(a1, ra[p], cw[p], wv[p], C0c, C1c, C2c, C3c, LOc, HIc, Hc);
    }
  };

  // ---- chunk 0: load + write buf0 ----
  uint4v pR = {};
  if (doR) pR = *(const uint4v*)(gR);
  uint4v pC0 = *(const uint4v*)(gC0);
  uint4v pC1 = *(const uint4v*)(gC1);
  float pw0 = 0.f, pw1 = 0.f;
  if (tid < 64) { pw0 = w2[Kb0 + 2 * tid]; pw1 = w2[Kb0 + 2 * tid + 1]; }
  wr(0, pR, pC0, pC1, pw0, pw1);
  __syncthreads();

  // ---- prefetch chunk 1 (T14), compute chunk 0 ----
  if (doR) pR = *(const uint4v*)(gR + 128);
  pC0 = *(const uint4v*)(gC0 + 128);
  pC1 = *(const uint4v*)(gC1 + 128);
  if (tid < 64) { pw0 = w2[Kb0 + 128 + 2 * tid]; pw1 = w2[Kb0 + 128 + 2 * tid + 1]; }
  comp(0);
  wr(1, pR, pC0, pC1, pw0, pw1);
  __syncthreads();

  // ---- prefetch chunk 2, compute chunk 1 ----
  if (doR) pR = *(const uint4v*)(gR + 256);
  pC0 = *(const uint4v*)(gC0 + 256);
  pC1 = *(const uint4v*)(gC1 + 256);
  if (tid < 64) { pw0 = w2[Kb0 + 256 + 2 * tid]; pw1 = w2[Kb0 + 256 + 2 * tid + 1]; }
  comp(1);
  wr(0, pR, pC0, pC1, pw0, pw1);
  __syncthreads();

  // ---- compute chunk 2 ----
  comp(0);

  // ---- epilogue: 2 partial sums -> atomics (4 contributions/addr) ----
  const size_t rowA = (size_t)(bz * 256 + it * 16 + row);
  const size_t base = rowA * 256 + jt * 64 + cg;
  unsafeAtomicAdd(&outm[base +  0], a0);
  unsafeAtomicAdd(&outm[base + 32], a1);
}

// ---------------- launch ----------------
extern "C" void kernel_launch(void* const* d_in, const int* in_sizes, int n_in,
                              void* d_out, int out_size, void* d_ws, size_t ws_size,
                              hipStream_t stream) {
  const float* hidden  = (const float*)d_in[0];
  const float* w_start = (const float*)d_in[1];
  const float* b_start = (const float*)d_in[2];
  const float* w_end   = (const float*)d_in[3];
  const float* b_end   = (const float*)d_in[4];
  const float* w1      = (const float*)d_in[5];
  const float* b1      = (const float*)d_in[6];
  const float* w2      = (const float*)d_in[7];
  const float* b2      = (const float*)d_in[8];

  float* out = (float*)d_out;
  char* ws = (char*)d_ws;
  unsigned short* wsR  = (unsigned short*)(ws);             // 1,572,864 B (f16)
  unsigned short* wsC  = (unsigned short*)(ws + 1572864);   // 1,572,864 B (f16)
  unsigned short* Wfmt = (unsigned short*)(ws + 3145728);   // 4,718,592 B (bf16)

  convert_kernel<<<dim3(6, 192), dim3(256), 0, stream>>>(w1, Wfmt);
  proj_kernel<<<dim3(48, 17), dim3(256), 0, stream>>>(
      hidden, Wfmt, b1, wsR, wsC, w_start, b_start, w_end, b_end, b2, out);
  match_kernel<<<dim3(4, 16, 8), dim3(512), 0, stream>>>(wsR, wsC, w2, out + 1024);
}